// Round 17
// baseline (188.187 us; speedup 1.0000x reference)
//
#include <hip/hip_runtime.h>
#include <hip/hip_bf16.h>
#include <math.h>

// ---------------------------------------------------------------------------
// LBANP encoder layer on MI355X (gfx950).
// Round 17: projx tile M 128 -> 64 (acc[2][4], LDS 24 KB, 4160 blocks,
// launch_bounds(256,5)) to double block-level latency hiding of the
// 2-phase staging stall. Everything else unchanged from round 16.
// ---------------------------------------------------------------------------

typedef __attribute__((ext_vector_type(8))) short bf16x8;   // 8 x bf16 (4 VGPRs)
typedef __attribute__((ext_vector_type(4))) float f32x4;
typedef long i64;
typedef __attribute__((ext_vector_type(2))) long i64x2;

#define DEVI __device__ __forceinline__

DEVI void load_lds16(const void* g, void* l) {
  __builtin_amdgcn_global_load_lds(
      (const __attribute__((address_space(1))) void*)g,
      (__attribute__((address_space(3))) void*)l, 16, 0, 0);
}

DEVI short bfbits(float x) {
  __hip_bfloat16 h = __float2bfloat16(x);
  return *reinterpret_cast<short*>(&h);
}

DEVI unsigned int fp8pk2(float a, float b) {
  return __builtin_amdgcn_cvt_pk_fp8_f32(a, b, 0, false) & 0xffff;
}

DEVI unsigned char fp8b(float x) {
  return (unsigned char)(__builtin_amdgcn_cvt_pk_fp8_f32(x, x, 0, false) & 0xff);
}

// byte position of logical col within a granule-interleaved 64B group
DEVI int gpos(int col) {
  const int g = (col >> 3) & 7;
  return (col & ~63) + (g & 3) * 16 + (g >> 2) * 8 + (col & 7);
}

// ---------------------------------------------------------------------------
// Split-K GEMM (bf16): P[z][M*N] = A[M, kseg] * Bt^T partials (f32).
// ---------------------------------------------------------------------------
__global__ __launch_bounds__(256, 4) void gemm_sk(
    const __hip_bfloat16* __restrict__ A, const __hip_bfloat16* __restrict__ Bt,
    float* __restrict__ P, int M, int N, int K) {
  const int nwg = gridDim.x * gridDim.y;
  const int lid = blockIdx.y * gridDim.x + blockIdx.x;
  const int work = (lid & 7) * (nwg >> 3) + (lid >> 3);
  const int n0 = (work % gridDim.x) * 128;
  const int m0 = (work / gridDim.x) * 128;
  const int KS = K / gridDim.z;
  const int kbeg = blockIdx.z * KS;

  const int t = threadIdx.x;
  const int w = t >> 6, l = t & 63;
  const int lr = l & 15, lk = l >> 4;
  const int wm = (w >> 1) * 64, wn = (w & 1) * 64;
  __shared__ __hip_bfloat16 Al[2][128 * 32];
  __shared__ __hip_bfloat16 Bl[2][128 * 32];

  f32x4 acc[4][4];
  const f32x4 z = {0.f, 0.f, 0.f, 0.f};
#pragma unroll
  for (int i = 0; i < 4; ++i)
#pragma unroll
    for (int j = 0; j < 4; ++j) acc[i][j] = z;

  const int srow = w * 16 + (l >> 2);
  const int scol = ((l & 3) ^ ((l >> 3) & 3)) * 8;
  const __hip_bfloat16* Ag = A + (size_t)(m0 + srow) * K + kbeg + scol;
  const __hip_bfloat16* Bg = Bt + (size_t)(n0 + srow) * K + kbeg + scol;

#define STAGE(buf, k0)                                                   \
  {                                                                      \
    load_lds16(Ag + (k0), (char*)Al[buf] + w * 1024);                    \
    load_lds16(Ag + (size_t)64 * K + (k0), (char*)Al[buf] + 4096 + w * 1024); \
    load_lds16(Bg + (k0), (char*)Bl[buf] + w * 1024);                    \
    load_lds16(Bg + (size_t)64 * K + (k0), (char*)Bl[buf] + 4096 + w * 1024); \
  }

  STAGE(0, 0);
  __syncthreads();
  int cur = 0;
  const int rs = (lk ^ ((lr >> 1) & 3)) * 16;
  for (int k0 = 0; k0 < KS; k0 += 32) {
    if (k0 + 32 < KS) STAGE(cur ^ 1, k0 + 32);
    bf16x8 af[4], bfr[4];
#pragma unroll
    for (int i = 0; i < 4; ++i)
      af[i] = *(const bf16x8*)((const char*)Al[cur] + ((wm + i * 16 + lr) * 64 + rs));
#pragma unroll
    for (int j = 0; j < 4; ++j)
      bfr[j] = *(const bf16x8*)((const char*)Bl[cur] + ((wn + j * 16 + lr) * 64 + rs));
#pragma unroll
    for (int i = 0; i < 4; ++i)
#pragma unroll
      for (int j = 0; j < 4; ++j)
        acc[i][j] = __builtin_amdgcn_mfma_f32_16x16x32_bf16(af[i], bfr[j], acc[i][j], 0, 0, 0);
    __syncthreads();
    cur ^= 1;
  }
#undef STAGE

  float* Pz = P + (size_t)blockIdx.z * M * N;
#pragma unroll
  for (int i = 0; i < 4; ++i) {
    const int row = m0 + wm + i * 16 + lk * 4;
#pragma unroll
    for (int j = 0; j < 4; ++j) {
      const int col = n0 + wn + j * 16 + lr;
#pragma unroll
      for (int r = 0; r < 4; ++r)
        Pz[(size_t)(row + r) * N + col] = acc[i][j][r];
    }
  }
}

// reduce split-K partials (float4): out = sum_sk P + bias + res  (grid 512x256)
__global__ __launch_bounds__(256) void reduce_sk(
    const float* __restrict__ P, const float* __restrict__ bias,
    const float* __restrict__ res, float* __restrict__ out, int SK) {
  const int i = (blockIdx.x * 256 + threadIdx.x) * 4;
  f32x4 v = *(const f32x4*)&bias[i & 511];
  const f32x4 rr = *(const f32x4*)&res[i];
  v += rr;
  for (int s = 0; s < SK; ++s) v += *(const f32x4*)&P[(size_t)s * 524288 + i];
  *(f32x4*)&out[i] = v;
}

// ---------------------------------------------------------------------------
// reduce split-K + LayerNorm, wave-per-row. Emits f32 x and bf16 LN(x).
// ---------------------------------------------------------------------------
__global__ __launch_bounds__(256) void reduce_ln_sk(
    const float* __restrict__ P, const float* __restrict__ bias,
    const float* __restrict__ res, float* __restrict__ xout,
    const float* __restrict__ w, const float* __restrict__ b,
    __hip_bfloat16* __restrict__ y, int SK) {
  const int row = blockIdx.x * 4 + (threadIdx.x >> 6);
  const int l = threadIdx.x & 63;
  const size_t base = (size_t)row * 512 + l * 8;
  f32x4 v0 = *(const f32x4*)&res[base];
  f32x4 v1 = *(const f32x4*)&res[base + 4];
  v0 += *(const f32x4*)&bias[l * 8];
  v1 += *(const f32x4*)&bias[l * 8 + 4];
  for (int s = 0; s < SK; ++s) {
    v0 += *(const f32x4*)&P[(size_t)s * 524288 + base];
    v1 += *(const f32x4*)&P[(size_t)s * 524288 + base + 4];
  }
  *(f32x4*)&xout[base] = v0;
  *(f32x4*)&xout[base + 4] = v1;
  float s1 = 0.f, s2 = 0.f;
#pragma unroll
  for (int e = 0; e < 4; ++e) {
    s1 += v0[e] + v1[e];
    s2 += v0[e] * v0[e] + v1[e] * v1[e];
  }
#pragma unroll
  for (int d = 1; d < 64; d <<= 1) {
    s1 += __shfl_xor(s1, d);
    s2 += __shfl_xor(s2, d);
  }
  const float mean = s1 * (1.f / 512.f);
  const float var = s2 * (1.f / 512.f) - mean * mean;
  const float rstd = rsqrtf(var + 1e-5f);
  const f32x4 w0 = *(const f32x4*)&w[l * 8], w1 = *(const f32x4*)&w[l * 8 + 4];
  const f32x4 b0 = *(const f32x4*)&b[l * 8], b1 = *(const f32x4*)&b[l * 8 + 4];
  bf16x8 o;
#pragma unroll
  for (int e = 0; e < 4; ++e) {
    o[e] = bfbits((v0[e] - mean) * rstd * w0[e] + b0[e]);
    o[e + 4] = bfbits((v1[e] - mean) * rstd * w1[e] + b1[e]);
  }
  *(bf16x8*)&y[base] = o;
}

// ---------------------------------------------------------------------------
// gemm_geglu: 64x128-tile bf16 GEMM with fused GEGLU epilogue (permuted w1).
// ---------------------------------------------------------------------------
__global__ __launch_bounds__(256, 4) void gemm_geglu(
    const __hip_bfloat16* __restrict__ A, const __hip_bfloat16* __restrict__ Bt,
    __hip_bfloat16* __restrict__ Cb, const float* __restrict__ bias) {
  const int K = 512;
  const int nwg = gridDim.x * gridDim.y;
  const int lid = blockIdx.y * gridDim.x + blockIdx.x;
  const int work = (lid & 7) * (nwg >> 3) + (lid >> 3);
  const int n0 = (work % gridDim.x) * 128;
  const int m0 = (work / gridDim.x) * 64;

  const int t = threadIdx.x;
  const int w = t >> 6, l = t & 63;
  const int lr = l & 15, lk = l >> 4;
  const int wm = (w >> 1) * 32, wn = (w & 1) * 64;
  __shared__ __hip_bfloat16 Al[2][64 * 32];
  __shared__ __hip_bfloat16 Bl[2][128 * 32];

  f32x4 acc[2][4];
  const f32x4 z = {0.f, 0.f, 0.f, 0.f};
#pragma unroll
  for (int i = 0; i < 2; ++i)
#pragma unroll
    for (int j = 0; j < 4; ++j) acc[i][j] = z;

  const int srow = w * 16 + (l >> 2);
  const int scol = ((l & 3) ^ ((l >> 3) & 3)) * 8;
  const __hip_bfloat16* Ag = A + (size_t)(m0 + srow) * K + scol;
  const __hip_bfloat16* Bg = Bt + (size_t)(n0 + srow) * K + scol;

#define STAGE(buf, k0)                                                   \
  {                                                                      \
    load_lds16(Ag + (k0), (char*)Al[buf] + w * 1024);                    \
    load_lds16(Bg + (k0), (char*)Bl[buf] + w * 1024);                    \
    load_lds16(Bg + (size_t)64 * K + (k0), (char*)Bl[buf] + 4096 + w * 1024); \
  }

  STAGE(0, 0);
  __syncthreads();
  int cur = 0;
  const int rs = (lk ^ ((lr >> 1) & 3)) * 16;
  for (int k0 = 0; k0 < K; k0 += 32) {
    if (k0 + 32 < K) STAGE(cur ^ 1, k0 + 32);
    bf16x8 af[2], bfr[4];
#pragma unroll
    for (int i = 0; i < 2; ++i)
      af[i] = *(const bf16x8*)((const char*)Al[cur] + ((wm + i * 16 + lr) * 64 + rs));
#pragma unroll
    for (int j = 0; j < 4; ++j)
      bfr[j] = *(const bf16x8*)((const char*)Bl[cur] + ((wn + j * 16 + lr) * 64 + rs));
#pragma unroll
    for (int i = 0; i < 2; ++i)
#pragma unroll
      for (int j = 0; j < 4; ++j)
        acc[i][j] = __builtin_amdgcn_mfma_f32_16x16x32_bf16(af[i], bfr[j], acc[i][j], 0, 0, 0);
    __syncthreads();
    cur ^= 1;
  }
#undef STAGE

  const int nb = (n0 + wn) >> 1;
  float ba[2], bg[2];
#pragma unroll
  for (int jj = 0; jj < 2; ++jj) {
    ba[jj] = bias[nb + jj * 16 + lr];
    bg[jj] = bias[2048 + nb + jj * 16 + lr];
  }
#pragma unroll
  for (int i = 0; i < 2; ++i) {
    const int row = m0 + wm + i * 16 + lk * 4;
#pragma unroll
    for (int jj = 0; jj < 2; ++jj) {
      const int col = nb + jj * 16 + lr;
#pragma unroll
      for (int r = 0; r < 4; ++r) {
        const float a = acc[i][jj][r] + ba[jj];
        const float g = acc[i][jj + 2][r] + bg[jj];
        const float ge = 0.5f * g * (1.f + erff(g * 0.70710678118f));
        Cb[(size_t)(row + r) * 2048 + col] = __float2bfloat16(a * ge);
      }
    }
  }
}

// ---------------------------------------------------------------------------
// projx (fp8, 64x128 tile): 1D grid 4160 = 4096 KV + 64 Q blocks.
// Inputs granule-interleaved fp8. Outputs: K half / Q -> fp8 x4 prescale,
// granule-interleaved; V half -> bf16 transposed. acc[2][4], LDS 24 KB.
// ---------------------------------------------------------------------------
__global__ __launch_bounds__(256, 5) void projx_kernel(
    const unsigned char* __restrict__ ctx8, const unsigned char* __restrict__ wkv8,
    unsigned char* __restrict__ K8, __hip_bfloat16* __restrict__ Vt,
    const unsigned char* __restrict__ xq8, const unsigned char* __restrict__ wq8,
    unsigned char* __restrict__ Q8) {
  const int nwg = gridDim.x;   // 4160, % 8 == 0
  const int lid = blockIdx.x;
  const int work = (lid & 7) * (nwg >> 3) + (lid >> 3);

  const unsigned char *A, *Bt;
  int m0, n0, mode;   // 0 = K half, 1 = V half, 2 = Q
  if (work < 4096) {
    m0 = (work >> 3) * 64;
    n0 = (work & 7) * 128;
    A = ctx8; Bt = wkv8;
    mode = (n0 < 512) ? 0 : 1;
  } else {
    const int idx = work - 4096;
    m0 = (idx >> 2) * 64;
    n0 = (idx & 3) * 128;
    A = xq8; Bt = wq8;
    mode = 2;
  }

  const int t = threadIdx.x;
  const int w = t >> 6, l = t & 63;
  const int lr = l & 15, lk = l >> 4;
  const int wm = (w >> 1) * 32, wn = (w & 1) * 64;
  __shared__ unsigned char Al[2][64 * 64];    // 4 KiB per buf
  __shared__ unsigned char Bl[2][128 * 64];   // 8 KiB per buf

  f32x4 acc[2][4];
  const f32x4 z = {0.f, 0.f, 0.f, 0.f};
#pragma unroll
  for (int i = 0; i < 2; ++i)
#pragma unroll
    for (int j = 0; j < 4; ++j) acc[i][j] = z;

  const int srow = w * 16 + (l >> 2);
  const int sc = ((l & 3) ^ ((l >> 3) & 3)) * 16;
  const unsigned char* Ag = A + (size_t)(m0 + srow) * 512 + sc;
  const unsigned char* Bg = Bt + (size_t)(n0 + srow) * 512 + sc;

#define STAGE(buf, kb)                                                   \
  {                                                                      \
    load_lds16(Ag + (kb), (char*)Al[buf] + w * 1024);                    \
    load_lds16(Bg + (kb), (char*)Bl[buf] + w * 1024);                    \
    load_lds16(Bg + (size_t)64 * 512 + (kb), (char*)Bl[buf] + 4096 + w * 1024); \
  }

  STAGE(0, 0);
  __syncthreads();
  int cur = 0;
  const int rs = (lk ^ ((lr >> 1) & 3)) * 16;
  for (int tt = 0; tt < 8; ++tt) {
    if (tt < 7) STAGE(cur ^ 1, (tt + 1) * 64);
    i64 af[2][2], bfr[2][4];
#pragma unroll
    for (int i = 0; i < 2; ++i) {
      const int ar = wm + i * 16 + lr;
      const i64x2 v = *(const i64x2*)((const char*)Al[cur] + ar * 64 + rs);
      af[0][i] = v[0];
      af[1][i] = v[1];
    }
#pragma unroll
    for (int j = 0; j < 4; ++j) {
      const int br = wn + j * 16 + lr;
      const i64x2 v = *(const i64x2*)((const char*)Bl[cur] + br * 64 + rs);
      bfr[0][j] = v[0];
      bfr[1][j] = v[1];
    }
#pragma unroll
    for (int i = 0; i < 2; ++i)
#pragma unroll
      for (int j = 0; j < 4; ++j) {
        acc[i][j] = __builtin_amdgcn_mfma_f32_16x16x32_fp8_fp8(af[0][i], bfr[0][j], acc[i][j], 0, 0, 0);
        acc[i][j] = __builtin_amdgcn_mfma_f32_16x16x32_fp8_fp8(af[1][i], bfr[1][j], acc[i][j], 0, 0, 0);
      }
    __syncthreads();
    cur ^= 1;
  }
#undef STAGE

  const float SCL = 0.0625f;          // undo weight x16
  const float SQK = SCL * 4.f;        // fp8 Q/K prescale x4
  if (mode == 0) {
#pragma unroll
    for (int i = 0; i < 2; ++i) {
      const int row = m0 + wm + i * 16 + lk * 4;
#pragma unroll
      for (int j = 0; j < 4; ++j) {
        const int bp = gpos(n0 + wn + j * 16 + lr);
#pragma unroll
        for (int r = 0; r < 4; ++r)
          K8[(size_t)(row + r) * 512 + bp] = fp8b(acc[i][j][r] * SQK);
      }
    }
  } else if (mode == 1) {
#pragma unroll
    for (int i = 0; i < 2; ++i) {
      const int row0 = m0 + wm + i * 16 + lk * 4;
      const int b = row0 >> 12;
      const int key0 = row0 & 4095;
#pragma unroll
      for (int j = 0; j < 4; ++j) {
        const int c = n0 + wn + j * 16 + lr - 512;
        const int hh = c >> 6, dh = c & 63;
        short4 pk;
        pk.x = bfbits(acc[i][j][0] * SCL);
        pk.y = bfbits(acc[i][j][1] * SCL);
        pk.z = bfbits(acc[i][j][2] * SCL);
        pk.w = bfbits(acc[i][j][3] * SCL);
        *(short4*)&Vt[((size_t)((b * 8 + hh) * 64 + dh) << 12) + key0] = pk;
      }
    }
  } else {
#pragma unroll
    for (int i = 0; i < 2; ++i) {
      const int row = m0 + wm + i * 16 + lk * 4;
#pragma unroll
      for (int j = 0; j < 4; ++j) {
        const int bp = gpos(n0 + wn + j * 16 + lr);
#pragma unroll
        for (int r = 0; r < 4; ++r)
          Q8[(size_t)(row + r) * 512 + bp] = fp8b(acc[i][j][r] * SQK);
      }
    }
  }
}

// ---------------------------------------------------------------------------
// proj (self-attn, bf16): 3-way epilogue by column.
// ---------------------------------------------------------------------------
__global__ __launch_bounds__(256, 4) void proj_kernel(
    const __hip_bfloat16* __restrict__ A, const __hip_bfloat16* __restrict__ Bt,
    __hip_bfloat16* __restrict__ Qb, __hip_bfloat16* __restrict__ Kb,
    __hip_bfloat16* __restrict__ Vt, int qcols, int rpb_shift) {
  const int nwg = gridDim.x * gridDim.y;
  const int lid = blockIdx.y * gridDim.x + blockIdx.x;
  const int work = (lid & 7) * (nwg >> 3) + (lid >> 3);
  const int n0 = (work % gridDim.x) * 128;
  const int m0 = (work / gridDim.x) * 128;
  const int K = 512;

  const int t = threadIdx.x;
  const int w = t >> 6, l = t & 63;
  const int lr = l & 15, lk = l >> 4;
  const int wm = (w >> 1) * 64, wn = (w & 1) * 64;
  __shared__ __hip_bfloat16 Al[2][128 * 32];
  __shared__ __hip_bfloat16 Bl[2][128 * 32];

  f32x4 acc[4][4];
  const f32x4 z = {0.f, 0.f, 0.f, 0.f};
#pragma unroll
  for (int i = 0; i < 4; ++i)
#pragma unroll
    for (int j = 0; j < 4; ++j) acc[i][j] = z;

  const int srow = w * 16 + (l >> 2);
  const int scol = ((l & 3) ^ ((l >> 3) & 3)) * 8;
  const __hip_bfloat16* Ag = A + (size_t)(m0 + srow) * K + scol;
  const __hip_bfloat16* Bg = Bt + (size_t)(n0 + srow) * K + scol;

#define STAGE(buf, k0)                                                   \
  {                                                                      \
    load_lds16(Ag + (k0), (char*)Al[buf] + w * 1024);                    \
    load_lds16(Ag + (size_t)64 * K + (k0), (char*)Al[buf] + 4096 + w * 1024); \
    load_lds16(Bg + (k0), (char*)Bl[buf] + w * 1024);                    \
    load_lds16(Bg + (size_t)64 * K + (k0), (char*)Bl[buf] + 4096 + w * 1024); \
  }

  STAGE(0, 0);
  __syncthreads();
  int cur = 0;
  const int rs = (lk ^ ((lr >> 1) & 3)) * 16;
  for (int k0 = 0; k0 < K; k0 += 32) {
    if (k0 + 32 < K) STAGE(cur ^ 1, k0 + 32);
    bf16x8 af[4], bfr[4];
#pragma unroll
    for (int i = 0; i < 4; ++i)
      af[i] = *(const bf16x8*)((const char*)Al[cur] + ((wm + i * 16 + lr) * 64 + rs));
#pragma unroll
    for (int j = 0; j < 4; ++j)
      bfr[j] = *(const bf16x8*)((const char*)Bl[cur] + ((wn + j * 16 + lr) * 64 + rs));
#pragma unroll
    for (int i = 0; i < 4; ++i)
#pragma unroll
      for (int j = 0; j < 4; ++j)
        acc[i][j] = __builtin_amdgcn_mfma_f32_16x16x32_bf16(af[i], bfr[j], acc[i][j], 0, 0, 0);
    __syncthreads();
    cur ^= 1;
  }
#undef STAGE

  if (n0 < qcols) {
#pragma unroll
    for (int i = 0; i < 4; ++i) {
      const int row = m0 + wm + i * 16 + lk * 4;
#pragma unroll
      for (int j = 0; j < 4; ++j) {
        const int col = n0 + wn + j * 16 + lr;
#pragma unroll
        for (int r = 0; r < 4; ++r)
          Qb[(size_t)(row + r) * 512 + col] = __float2bfloat16(acc[i][j][r]);
      }
    }
  } else if (n0 < qcols + 512) {
#pragma unroll
    for (int i = 0; i < 4; ++i) {
      const int row = m0 + wm + i * 16 + lk * 4;
#pragma unroll
      for (int j = 0; j < 4; ++j) {
        const int col = n0 + wn + j * 16 + lr - qcols;
#pragma unroll
        for (int r = 0; r < 4; ++r)
          Kb[(size_t)(row + r) * 512 + col] = __float2bfloat16(acc[i][j][r]);
      }
    }
  } else {
    const int rpb = 1 << rpb_shift;
#pragma unroll
    for (int i = 0; i < 4; ++i) {
      const int row0 = m0 + wm + i * 16 + lk * 4;
      const int b = row0 >> rpb_shift;
      const int key0 = row0 & (rpb - 1);
#pragma unroll
      for (int j = 0; j < 4; ++j) {
        const int c = n0 + wn + j * 16 + lr - qcols - 512;
        const int hh = c >> 6, dh = c & 63;
        short4 pk;
        pk.x = bfbits(acc[i][j][0]);
        pk.y = bfbits(acc[i][j][1]);
        pk.z = bfbits(acc[i][j][2]);
        pk.w = bfbits(acc[i][j][3]);
        *(short4*)&Vt[((size_t)((b * 8 + hh) * 64 + dh) << rpb_shift) + key0] = pk;
      }
    }
  }
}

// ---------------------------------------------------------------------------
// Key-split flash attention, static-max softmax; bf16 partials, f32 row sums.
// QK8=1: Q/K fp8 (granule-interleaved, x4 prescaled), QK^T on fp8 MFMA.
// QK8=0: bf16 path (self-attention). If Od != nullptr (S==1): direct write.
// ---------------------------------------------------------------------------
template <int QK8>
__global__ __launch_bounds__(256) void attn_split_kernel(
    const void* __restrict__ Qp, const void* __restrict__ Kp,
    const __hip_bfloat16* __restrict__ Vt,
    __hip_bfloat16* __restrict__ Opart, float* __restrict__ Lv,
    __hip_bfloat16* __restrict__ Od,
    int chunk, int rows_per_b, int S) {
  const float SC2 = QK8 ? (0.18033688f / 16.f) : 0.18033688f;
  const int h = blockIdx.x, b = blockIdx.y, s = blockIdx.z;
  const int t = threadIdx.x;
  const int w = t >> 6, l = t & 63;
  const int lr = l & 15, lk = l >> 4;
  __shared__ unsigned char Kraw[QK8 ? 4096 : 8192];
  __shared__ __hip_bfloat16 Vl[64 * 64];
  __shared__ __hip_bfloat16 Pl[4][32 * 64];

  bf16x8 qf[2][2];
  i64 qf8[2][2];
  if constexpr (QK8) {
    const unsigned char* q8 = (const unsigned char*)Qp;
#pragma unroll
    for (int mf = 0; mf < 2; ++mf) {
      const i64x2 qv = *(const i64x2*)&q8[(size_t)(b * 128 + w * 32 + mf * 16 + lr) * 512 +
                                          h * 64 + lk * 16];
      qf8[mf][0] = qv[0];
      qf8[mf][1] = qv[1];
    }
  } else {
    const __hip_bfloat16* Q = (const __hip_bfloat16*)Qp;
#pragma unroll
    for (int mf = 0; mf < 2; ++mf)
#pragma unroll
      for (int kf = 0; kf < 2; ++kf)
        qf[mf][kf] = *(const bf16x8*)&Q[(size_t)(b * 128 + w * 32 + mf * 16 + lr) * 512 +
                                        h * 64 + kf * 32 + lk * 8];
  }

  f32x4 o[2][4];
  const f32x4 z = {0.f, 0.f, 0.f, 0.f};
#pragma unroll
  for (int mf = 0; mf < 2; ++mf)
#pragma unroll
    for (int nf = 0; nf < 4; ++nf) o[mf][nf] = z;
  float lsum[2][4];
#pragma unroll
  for (int mf = 0; mf < 2; ++mf)
#pragma unroll
    for (int r = 0; r < 4; ++r) lsum[mf][r] = 0.f;

  const __hip_bfloat16* vtb = Vt + (size_t)(b * 8 + h) * 64 * rows_per_b;
  char* pw = (char*)Pl[w];
  const int srow = l >> 3;
  const int sslot = (l & 7) ^ srow;
  const int jend = s * chunk + chunk;

  for (int j0 = s * chunk; j0 < jend; j0 += 64) {
    __syncthreads();
    if constexpr (QK8) {
      const unsigned char* k8b = (const unsigned char*)Kp + (size_t)b * rows_per_b * 512;
      const int kr = t >> 2, kslot = t & 3;
      const int src = kslot ^ ((kr >> 1) & 3);
      load_lds16(&k8b[(size_t)(j0 + kr) * 512 + h * 64 + src * 16], (char*)Kraw + t * 16);
#pragma unroll
      for (int p = 0; p < 2; ++p) {
        const int row = p * 32 + w * 8 + srow;
        load_lds16(&vtb[(size_t)row * rows_per_b + j0 + sslot * 8],
                   (char*)Vl + p * 4096 + w * 1024);
      }
    } else {
      const __hip_bfloat16* kvb = (const __hip_bfloat16*)Kp + (size_t)b * rows_per_b * 512;
#pragma unroll
      for (int p = 0; p < 2; ++p) {
        const int row = p * 32 + w * 8 + srow;
        load_lds16(&kvb[(size_t)(j0 + row) * 512 + h * 64 + sslot * 8],
                   (char*)Kraw + p * 4096 + w * 1024);
        load_lds16(&vtb[(size_t)row * rows_per_b + j0 + sslot * 8],
                   (char*)Vl + p * 4096 + w * 1024);
      }
    }
    __syncthreads();

    f32x4 sc[2][4];
#pragma unroll
    for (int mf = 0; mf < 2; ++mf)
#pragma unroll
      for (int nf = 0; nf < 4; ++nf) sc[mf][nf] = z;
    __builtin_amdgcn_s_setprio(1);
    if constexpr (QK8) {
      const int rs8 = (lk ^ ((lr >> 1) & 3)) * 16;
#pragma unroll
      for (int nf = 0; nf < 4; ++nf) {
        const int key = nf * 16 + lr;
        const i64x2 kv = *(const i64x2*)((const char*)Kraw + key * 64 + rs8);
#pragma unroll
        for (int mf = 0; mf < 2; ++mf) {
          sc[mf][nf] = __builtin_amdgcn_mfma_f32_16x16x32_fp8_fp8(qf8[mf][0], kv[0], sc[mf][nf], 0, 0, 0);
          sc[mf][nf] = __builtin_amdgcn_mfma_f32_16x16x32_fp8_fp8(qf8[mf][1], kv[1], sc[mf][nf], 0, 0, 0);
        }
      }
    } else {
#pragma unroll
      for (int kf = 0; kf < 2; ++kf) {
        bf16x8 kb[4];
#pragma unroll
        for (int nf = 0; nf < 4; ++nf) {
          const int key = nf * 16 + lr;
          kb[nf] = *(const bf16x8*)((const char*)Kraw +
                    (key * 128 + (((kf * 4 + lk) ^ (key & 7)) * 16)));
        }
#pragma unroll
        for (int mf = 0; mf < 2; ++mf)
#pragma unroll
          for (int nf = 0; nf < 4; ++nf)
            sc[mf][nf] = __builtin_amdgcn_mfma_f32_16x16x32_bf16(qf[mf][kf], kb[nf], sc[mf][nf], 0, 0, 0);
      }
    }
    __builtin_amdgcn_s_setprio(0);

#pragma unroll
    for (int mf = 0; mf < 2; ++mf)
#pragma unroll
      for (int nf = 0; nf < 4; ++nf)
#pragma unroll
        for (int r = 0; r < 4; ++r) {
          const float p = exp2f(sc[mf][nf][r] * SC2);
          sc[mf][nf][r] = p;
          lsum[mf][r] += p;
        }

#pragma unroll
    for (int mf = 0; mf < 2; ++mf)
#pragma unroll
      for (int r = 0; r < 4; ++r) {
        const int prow = mf * 16 + lk * 4 + r;
#pragma unroll
        for (int nf = 0; nf < 4; ++nf) {
          const int pcol = nf * 16 + lr;
          *(__hip_bfloat16*)(pw + ((prow * 128 + pcol * 2) ^ ((prow & 7) << 4))) =
              __float2bfloat16(sc[mf][nf][r]);
        }
      }

    __builtin_amdgcn_s_setprio(1);
#pragma unroll
    for (int kf = 0; kf < 2; ++kf) {
      bf16x8 pa[2], vb[4];
#pragma unroll
      for (int mf = 0; mf < 2; ++mf) {
        const int prow = mf * 16 + lr;
        pa[mf] = *(const bf16x8*)(pw + ((prow * 128 + (kf * 4 + lk) * 16) ^ ((prow & 7) << 4)));
      }
#pragma unroll
      for (int nf = 0; nf < 4; ++nf) {
        const int dh = nf * 16 + lr;
        vb[nf] = *(const bf16x8*)((char*)Vl +
                  (dh * 128 + (((kf * 4 + lk) ^ (dh & 7)) * 16)));
      }
#pragma unroll
      for (int mf = 0; mf < 2; ++mf)
#pragma unroll
        for (int nf = 0; nf < 4; ++nf)
          o[mf][nf] = __builtin_amdgcn_mfma_f32_16x16x32_bf16(pa[mf], vb[nf], o[mf][nf], 0, 0, 0);
    }
    __builtin_amdgcn_s_setprio(0);
  }

  const int part = (b * 8 + h) * S + s;
  __hip_bfloat16* op = Opart + (size_t)part * 8192;
#pragma unroll
  for (int mf = 0; mf < 2; ++mf)
#pragma unroll
    for (int r = 0; r < 4; ++r) {
      float ls = lsum[mf][r];
      ls += __shfl_xor(ls, 1);
      ls += __shfl_xor(ls, 2);
      ls += __shfl_xor(ls, 4);
      ls += __shfl_xor(ls, 8);
      const int row = w * 32 + mf * 16 + lk * 4 + r;
      if (Od) {
        const float inv = 1.f / ls;
#pragma unroll
        for (int nf = 0; nf < 4; ++nf)
          Od[(size_t)(b * 128 + row) * 512 + h * 64 + nf * 16 + lr] =
              __float2bfloat16(o[mf][nf][r] * inv);
      } else {
#pragma unroll
        for (int nf = 0; nf < 4; ++nf)
          op[(size_t)row * 64 + nf * 16 + lr] = __float2bfloat16(o[mf][nf][r]);
        if (lr == 0) Lv[(size_t)part * 128 + row] = ls;
      }
    }
}

// combine (vectorized): thread t handles cols 2t, 2t+1 of its row.
__global__ __launch_bounds__(256) void attn_combine_kernel(
    const __hip_bfloat16* __restrict__ Opart, const float* __restrict__ Lv,
    __hip_bfloat16* __restrict__ O, int S) {
  const int row = blockIdx.x;
  const int b = row >> 7, i = row & 127;
  const int t = threadIdx.x;
  const int h = t >> 5, dh0 = (t * 2) & 63;
  const int pbase = (b * 8 + h) * S;
  float L = 0.f, v0 = 0.f, v1 = 0.f;
  for (int s = 0; s < S; ++s) {
    L += Lv[(size_t)(pbase + s) * 128 + i];
    const __hip_bfloat16* p = &Opart[((size_t)(pbase + s) * 128 + i) * 64 + dh0];
    const ushort2 u = *(const ushort2*)p;
    const unsigned int b0 = (unsigned int)u.x << 16, b1 = (unsigned int)u.y << 16;
    v0 += *(const float*)&b0;
    v1 += *(const float*)&b1;
  }
  const float inv = 1.f / L;
  ushort2 out;
  out.x = (unsigned short)bfbits(v0 * inv);
  out.y = (unsigned short)bfbits(v1 * inv);
  *(ushort2*)&O[(size_t)row * 512 + t * 2] = out;
}

// ---------------------------------------------------------------------------
// wave-per-row LayerNorm -> fp8, granule-interleaved store.
// ---------------------------------------------------------------------------
DEVI void ln_wave_q(const float* __restrict__ x, const float* __restrict__ w,
                    const float* __restrict__ bb, unsigned char* __restrict__ y,
                    int row) {
  const int l = threadIdx.x & 63;
  const size_t base = (size_t)row * 512 + l * 8;
  const f32x4 v0 = *(const f32x4*)&x[base];
  const f32x4 v1 = *(const f32x4*)&x[base + 4];
  float s = 0.f, sq = 0.f;
#pragma unroll
  for (int e = 0; e < 4; ++e) {
    s += v0[e] + v1[e];
    sq += v0[e] * v0[e] + v1[e] * v1[e];
  }
#pragma unroll
  for (int d = 1; d < 64; d <<= 1) {
    s += __shfl_xor(s, d);
    sq += __shfl_xor(sq, d);
  }
  const float mean = s * (1.f / 512.f);
  const float var = sq * (1.f / 512.f) - mean * mean;
  const float rstd = rsqrtf(var + 1e-5f);
  const f32x4 w0 = *(const f32x4*)&w[l * 8], w1 = *(const f32x4*)&w[l * 8 + 4];
  const f32x4 b0 = *(const f32x4*)&bb[l * 8], b1 = *(const f32x4*)&bb[l * 8 + 4];
  float yv[8];
#pragma unroll
  for (int e = 0; e < 4; ++e) {
    yv[e] = (v0[e] - mean) * rstd * w0[e] + b0[e];
    yv[e + 4] = (v1[e] - mean) * rstd * w1[e] + b1[e];
  }
  uint2 pk;
  pk.x = fp8pk2(yv[0], yv[1]) | (fp8pk2(yv[2], yv[3]) << 16);
  pk.y = fp8pk2(yv[4], yv[5]) | (fp8pk2(yv[6], yv[7]) << 16);
  const int gg = l & 7;
  const size_t wb = (size_t)row * 512 + (l >> 3) * 64 +
                    ((gg & 3) * 2 + (gg >> 2)) * 8;
  *(uint2*)&y[wb] = pk;
}

// ---------------------------------------------------------------------------
// prep: weight-convert (blocks 0..8191; w1 PERMUTED; set-0 wq/wkv -> fp8 x16,
// k-granule-interleaved) + wave-per-row LNs -> fp8 (blocks 8192+).
// ---------------------------------------------------------------------------
struct WcvtDesc { const float* src[10]; __hip_bfloat16* dst[10]; };

__global__ __launch_bounds__(256) void prep_kernel(
    WcvtDesc d, unsigned char* __restrict__ wq8, unsigned char* __restrict__ wkv8,
    const float* __restrict__ lat, const float* __restrict__ lw,
    const float* __restrict__ lb, unsigned char* __restrict__ xq8,
    const float* __restrict__ ctx, const float* __restrict__ cw,
    const float* __restrict__ cb, unsigned char* __restrict__ cn8) {
  if (blockIdx.x >= 8192) {
    const int row = (blockIdx.x - 8192) * 4 + (threadIdx.x >> 6);
    if (row < 1024)
      ln_wave_q(lat, lw, lb, xq8, row);
    else
      ln_wave_q(ctx, cw, cb, cn8, row - 1024);
    return;
  }
  int tile = blockIdx.x;
  const int set = tile >> 12;
  tile &= 4095;
  int wi0, K, N, base;
  if (tile < 256)       { wi0 = 0; K = 512;  N = 512;  base = 0; }
  else if (tile < 768)  { wi0 = 1; K = 512;  N = 1024; base = 256; }
  else if (tile < 1024) { wi0 = 2; K = 512;  N = 512;  base = 768; }
  else if (tile < 3072) { wi0 = 3; K = 512;  N = 4096; base = 1024; }
  else                  { wi0 = 4; K = 2048; N = 512;  base = 3072; }
  const bool permute = (wi0 == 3);
  const bool tofp8 = (set == 0 && wi0 < 2);
  const int wi = wi0 + set * 5;
  const int rel = tile - base;
  const int ntx = N >> 5;
  const int n0 = (rel % ntx) * 32, k0 = (rel / ntx) * 32;
  const int sn0 = permute ? (((n0 >> 6) << 5) + ((n0 & 32) ? 2048 : 0)) : n0;
  const float* W = d.src[wi];
  __shared__ float tl[32][33];
  const int tx = threadIdx.x & 31, ty = threadIdx.x >> 5;
#pragma unroll
  for (int j = 0; j < 4; ++j)
    tl[ty + j * 8][tx] = W[(size_t)(k0 + ty + j * 8) * N + sn0 + tx];
  __syncthreads();
  if (tofp8) {
    unsigned char* Wq = (wi0 == 0) ? wq8 : wkv8;
    const int k = k0 + tx;
    const int gg = (k >> 3) & 7;
    const int kp = (k & ~63) + ((gg & 3) * 2 + (gg >> 2)) * 8 + (k & 7);
#pragma unroll
    for (int j = 0; j < 4; ++j)
      Wq[(size_t)(n0 + ty + j * 8) * 512 + kp] = fp8b(tl[tx][ty + j * 8] * 16.f);
  } else {
    __hip_bfloat16* Wt = d.dst[wi];
#pragma unroll
    for (int j = 0; j < 4; ++j)
      Wt[(size_t)(n0 + ty + j * 8) * K + k0 + tx] = __float2bfloat16(tl[tx][ty + j * 8]);
  }
}

// ---------------------------------------------------------------------------
extern "C" void kernel_launch(void* const* d_in, const int* in_sizes, int n_in,
                              void* d_out, int out_size, void* d_ws, size_t ws_size,
                              hipStream_t stream) {
  (void)in_sizes; (void)n_in; (void)out_size; (void)ws_size;
  const float* context = (const float*)d_in[0];
  const float* latents = (const float*)d_in[1];
  const float* ca_ln_w = (const float*)d_in[2];
  const float* ca_ln_b = (const float*)d_in[3];
  const float* ca_lnc_w = (const float*)d_in[4];
  const float* ca_lnc_b = (const float*)d_in[5];
  const float* ca_wq = (const float*)d_in[6];
  const float* ca_wkv = (const float*)d_in[7];
  const float* ca_wo = (const float*)d_in[8];
  const float* ca_bo = (const float*)d_in[9];
  const float* cf_ln_w = (const float*)d_in[10];
  const float* cf_ln_b = (const float*)d_in[11];
  const float* cf_w1 = (const float*)d_in[12];
  const float* cf_b1 = (const float*)d_in[13];
  const float* cf_w2 = (const float*)d_in[14];
  const float* cf_b2 = (const float*)d_in[15];
  const float* sa_ln_w = (const float*)d_in[16];
  const float* sa_ln_b = (const float*)d_in[17];
  const float* sa_wq = (const float*)d_in[18];
  const float* sa_wkv = (const float*)d_in[19];
  const float* sa_wo = (const float*)d_in[20];
  const float* sa_bo = (const float*)d_in[21];
  const float* lf_ln_w = (const float*)d_in[22];
  const float* lf_ln_b = (const float*)d_in[23];
  const float* lf_w1 = (const float*)d_in[24];
  const float* lf_b1 = (const float*)d_in[25];
  const float* lf_w2 = (const float*)d_in[26];
  const float* lf_b2 = (const float*)d_in[27];

  typedef __hip_bfloat16 bf;
  char* ws = (char*)d_ws;
  size_t off = 0;
  auto alloc = [&](size_t bytes) -> void* {
    void* p = ws + off;
    off += (bytes + 255) & ~(size_t)255;
    return p;
  };
  bf* wq1t = (bf*)alloc((size_t)512 * 512 * 2);     // unused (fp8 path)
  bf* wkv1t = (bf*)alloc((size_t)1024 * 512 * 2);   // unused (fp8 path)
  bf* wo1t = (bf*)alloc((size_t)512 * 512 * 2);
  bf* w1ct = (bf*)alloc((size_t)4096 * 512 * 2);
  bf* w2ct = (bf*)alloc((size_t)512 * 2048 * 2);
  bf* wq2t = (bf*)alloc((size_t)512 * 512 * 2);
  bf* wkv2t = (bf*)alloc((size_t)1024 * 512 * 2);
  bf* wo2t = (bf*)alloc((size_t)512 * 512 * 2);
  bf* w1lt = (bf*)alloc((size_t)4096 * 512 * 2);
  bf* w2lt = (bf*)alloc((size_t)512 * 2048 * 2);
  unsigned char* wq8 = (unsigned char*)alloc((size_t)512 * 512);
  unsigned char* wkv8 = (unsigned char*)alloc((size_t)1024 * 512);
  unsigned char* cn8 = (unsigned char*)alloc((size_t)32768 * 512);   // 16.8 MB
  unsigned char* xq8 = (unsigned char*)alloc((size_t)1024 * 512);
  unsigned char* k8 = (unsigned char*)alloc((size_t)32768 * 512);    // cross K fp8
  unsigned char* q8 = (unsigned char*)alloc((size_t)1024 * 512);     // cross Q fp8
  bf* cn = (bf*)alloc((size_t)32768 * 512 * 2);     // reuse region (33.5 MB)
  bf* vt = (bf*)alloc((size_t)64 * 64 * 4096 * 2);  // cross V^T
  bf* kb2 = (bf*)alloc((size_t)1024 * 512 * 2);     // self K
  bf* vt2 = (bf*)alloc((size_t)64 * 64 * 128 * 2);  // self V^T
  float* lv = (float*)alloc((size_t)1024 * 128 * 4);
  float* skq = (float*)alloc((size_t)4 * 1024 * 512 * 4);
  bf* xnb = (bf*)alloc((size_t)1024 * 512 * 2);
  bf* aob = (bf*)alloc((size_t)1024 * 512 * 2);
  bf* q2b = (bf*)alloc((size_t)1024 * 512 * 2);
  bf* ao2b = (bf*)alloc((size_t)1024 * 512 * 2);
  float* x1 = (float*)alloc((size_t)1024 * 512 * 4);
  float* x2 = (float*)alloc((size_t)1024 * 512 * 4);
  float* x3 = (float*)alloc((size_t)1024 * 512 * 4);
  bf* x2n = (bf*)alloc((size_t)1024 * 512 * 2);
  bf* x3n = (bf*)alloc((size_t)1024 * 512 * 2);
  // cn region time-disjoint reuse:
  bf* opart = cn;                                  // attn bf16 partials (16.8 MB)
  float* skp = (float*)cn;                         // FFN-down SK=8 partials (16.8 MB)
  bf* agb = (bf*)((char*)cn + 17 * 1024 * 1024);   // GEGLU out (4.2 MB)

  WcvtDesc wd;
  wd.src[0] = ca_wq;  wd.dst[0] = wq1t;
  wd.src[1] = ca_wkv; wd.dst[1] = wkv1t;
  wd.src[2] = ca_wo;  wd.dst[2] = wo1t;
  wd.src[3] = cf_w1;  wd.dst[3] = w1ct;
  wd.src[4] = cf_w2;  wd.dst[4] = w2ct;
  wd.src[5] = sa_wq;  wd.dst[5] = wq2t;
  wd.src[6] = sa_wkv; wd.dst[6] = wkv2t;
  wd.src[7] = sa_wo;  wd.dst[7] = wo2t;
  wd.src[8] = lf_w1;  wd.dst[8] = w1lt;
  wd.src[9] = lf_w2;  wd.dst[9] = w2lt;

  // --- prep: weight convert (+fp8 cross wq/wkv) + wave-per-row LNs -> fp8 ---
  prep_kernel<<<8192 + 8448, 256, 0, stream>>>(
      wd, wq8, wkv8, latents, ca_ln_w, ca_ln_b, xq8,
      context, ca_lnc_w, ca_lnc_b, cn8);

  // --- sublayer 1: cross attention (fp8 Q/K end-to-end) ---
  projx_kernel<<<4160, 256, 0, stream>>>(cn8, wkv8, k8, vt, xq8, wq8, q8);
  attn_split_kernel<1><<<dim3(8, 8, 16), 256, 0, stream>>>(q8, k8, vt, opart, lv, nullptr, 256, 4096, 16);
  attn_combine_kernel<<<1024, 256, 0, stream>>>(opart, lv, aob, 16);
  gemm_sk<<<dim3(4, 8, 4), 256, 0, stream>>>(aob, wo1t, skq, 1024, 512, 512);
  reduce_ln_sk<<<256, 256, 0, stream>>>(skq, ca_bo, latents, x1, cf_ln_w, cf_ln_b, xnb, 4);

  // --- sublayer 2: cross FFN (GEGLU fused up-proj, SK=8 down-proj) ---
  gemm_geglu<<<dim3(32, 16), 256, 0, stream>>>(xnb, w1ct, agb, cf_b1);
  gemm_sk<<<dim3(4, 8, 8), 256, 0, stream>>>(agb, w2ct, skp, 1024, 512, 2048);
  reduce_ln_sk<<<256, 256, 0, stream>>>(skp, cf_b2, x1, x2, sa_ln_w, sa_ln_b, x2n, 8);

  // --- sublayer 3: latent self-attention (bf16, merged QKV, direct write) ---
  proj_kernel<<<dim3(12, 8), 256, 0, stream>>>(x2n, wq2t, q2b, kb2, vt2, 512, 7);
  attn_split_kernel<0><<<dim3(8, 8, 1), 256, 0, stream>>>(q2b, kb2, vt2, nullptr, nullptr, ao2b, 128, 128, 1);
  gemm_sk<<<dim3(4, 8, 4), 256, 0, stream>>>(ao2b, wo2t, skq, 1024, 512, 512);
  reduce_ln_sk<<<256, 256, 0, stream>>>(skq, sa_bo, x2, x3, lf_ln_w, lf_ln_b, x3n, 4);

  // --- sublayer 4: latent FFN (GEGLU fused up-proj, SK=8 down-proj) ---
  gemm_geglu<<<dim3(32, 16), 256, 0, stream>>>(x3n, w1lt, agb, lf_b1);
  gemm_sk<<<dim3(4, 8, 8), 256, 0, stream>>>(agb, w2lt, skp, 1024, 512, 2048);
  reduce_sk<<<512, 256, 0, stream>>>(skp, lf_b2, x3, (float*)d_out, 8);
}